// Round 7
// baseline (3272.961 us; speedup 1.0000x reference)
//
#include <hip/hip_runtime.h>
#include <stdint.h>

#define NPTS 8192
#define NS   2048
#define KNNK 32

typedef unsigned long long u64;
typedef float f32x2 __attribute__((ext_vector_type(2)));

// DPP-based 64-lane reduces (gfx9 ctrls kept on CDNA). After the 6 steps
// lanes 48..63 hold the full 64-lane result (lane 63 used).
__device__ __forceinline__ float wave_max_f32_dpp(float x) {
    int t;
    t = __builtin_amdgcn_update_dpp(0, __float_as_int(x), 0xB1, 0xF, 0xF, false);
    x = fmaxf(x, __int_as_float(t));
    t = __builtin_amdgcn_update_dpp(0, __float_as_int(x), 0x4E, 0xF, 0xF, false);
    x = fmaxf(x, __int_as_float(t));
    t = __builtin_amdgcn_update_dpp(0, __float_as_int(x), 0x141, 0xF, 0xF, false);
    x = fmaxf(x, __int_as_float(t));
    t = __builtin_amdgcn_update_dpp(0, __float_as_int(x), 0x140, 0xF, 0xF, false);
    x = fmaxf(x, __int_as_float(t));
    // non-written lanes keep old=0; d2>=0 so max(x,0)=x is a no-op
    t = __builtin_amdgcn_update_dpp(0, __float_as_int(x), 0x142, 0xF, 0xF, false);
    x = fmaxf(x, __int_as_float(t));
    t = __builtin_amdgcn_update_dpp(0, __float_as_int(x), 0x143, 0xF, 0xF, false);
    x = fmaxf(x, __int_as_float(t));
    return x;
}

__device__ __forceinline__ int wave_min_i32_dpp(int x) {
    const int INF = 0x7FFFFFFF;
    int t;
    t = __builtin_amdgcn_update_dpp(INF, x, 0xB1, 0xF, 0xF, false);
    x = t < x ? t : x;
    t = __builtin_amdgcn_update_dpp(INF, x, 0x4E, 0xF, 0xF, false);
    x = t < x ? t : x;
    t = __builtin_amdgcn_update_dpp(INF, x, 0x141, 0xF, 0xF, false);
    x = t < x ? t : x;
    t = __builtin_amdgcn_update_dpp(INF, x, 0x140, 0xF, 0xF, false);
    x = t < x ? t : x;
    t = __builtin_amdgcn_update_dpp(INF, x, 0x142, 0xF, 0xF, false);
    x = t < x ? t : x;
    t = __builtin_amdgcn_update_dpp(INF, x, 0x143, 0xF, 0xF, false);
    x = t < x ? t : x;
    return x;
}

// ============================ FPS =============================
// R6 structure, but ZERO global memory ops inside the loop: __syncthreads
// drains vmcnt(0), so an in-loop HBM store put ~300-900 cy on the critical
// path of every iteration. tid0 now stores only the winning u16 index to
// LDS; one cooperative coalesced out_xyz write after the loop.
// Exactness unchanged: rn ops (no contraction), sum order ((x+y)+z),
// argmax w/ lowest-index tie-break via M-match + i32 min (jnp.argmax).
__global__ __launch_bounds__(512)
void fps_kernel(const float* __restrict__ pts,
                float* __restrict__ out_xyz)
{
#pragma clang fp contract(off)
    const int bt  = blockIdx.x;        // b*4 + t0
    const int tid = threadIdx.x;
    const float* frame = pts + (size_t)bt * NPTS * 6;

    __shared__ float4 p4[NPTS];            // 128 KB coords copy
    __shared__ unsigned short selidx[NS];  // 4 KB selection history
    __shared__ float wmaxs[8];
    __shared__ unsigned selIdx[2];

    f32x2 x2[8], y2[8], z2[8], dd2[8];
#pragma unroll
    for (int j = 0; j < 16; ++j) {
        int n = j * 512 + tid;
        float x = frame[n*6+0], y = frame[n*6+1], z = frame[n*6+2];
        x2[j >> 1][j & 1] = x;
        y2[j >> 1][j & 1] = y;
        z2[j >> 1][j & 1] = z;
        dd2[j >> 1][j & 1] = 3.4028234663852886e38f;
        p4[n] = make_float4(x, y, z, 0.0f);
    }
    if (tid < 2) selIdx[tid] = 0x7FFFFFFFu;
    if (tid == 0) selidx[0] = 0;       // selection 0 = point 0
    __syncthreads();
    float sx = p4[0].x, sy = p4[0].y, sz = p4[0].z;

    for (int i = 1; i < NS; ++i) {
        const int pi = i & 1;
        // packed update vs previous selection, packed min/max accumulate
        f32x2 sxv = {sx, sx}, syv = {sy, sy}, szv = {sz, sz};
        f32x2 m2 = {0.0f, 0.0f};
#pragma unroll
        for (int q = 0; q < 8; ++q) {
            f32x2 dx = x2[q] - sxv;
            f32x2 dy = y2[q] - syv;
            f32x2 dz = z2[q] - szv;
            f32x2 dd = (dx*dx + dy*dy) + dz*dz;
            f32x2 nd;
            nd[0] = fminf(dd2[q][0], dd[0]);
            nd[1] = fminf(dd2[q][1], dd[1]);
            dd2[q] = nd;
            m2[0] = fmaxf(m2[0], nd[0]);
            m2[1] = fmaxf(m2[1], nd[1]);
        }
        float mloc = fmaxf(m2[0], m2[1]);
        // wave max (f32); lane 63 holds the full-wave result
        float wM = wave_max_f32_dpp(mloc);
        if ((tid & 63) == 63) wmaxs[tid >> 6] = wM;
        __syncthreads();               // A: wmaxs visible (LDS-only drain)
        float4 w0 = *(const float4*)&wmaxs[0];
        float4 w1 = *(const float4*)&wmaxs[4];
        float M = fmaxf(fmaxf(fmaxf(w0.x, w0.y), fmaxf(w0.z, w0.w)),
                        fmaxf(fmaxf(w1.x, w1.y), fmaxf(w1.z, w1.w)));
        // only wave(s) containing the global max do the index work
        bool match = (mloc == M);
        if (__any(match)) {
            unsigned mask = 0;
#pragma unroll
            for (int j = 0; j < 16; ++j)
                mask |= (dd2[j >> 1][j & 1] == M) ? (1u << j) : 0u;
            int bestn = mask ? (int)(__builtin_ctz(mask) * 512 + tid)
                             : 0x7FFFFFFF;
            int wI = wave_min_i32_dpp(bestn);
            if ((tid & 63) == 63) atomicMin(&selIdx[pi], (unsigned)wI);
        }
        __syncthreads();               // B: selIdx final (LDS-only drain)
        unsigned idx = selIdx[pi];
        if (tid == 0) {
            selIdx[pi ^ 1] = 0x7FFFFFFFu;            // for iter i+1
            selidx[i] = (unsigned short)idx;         // history, LDS only
        }
        float4 c = p4[idx];            // broadcast ds_read_b128
        sx = c.x; sy = c.y; sz = c.z;
    }
    __syncthreads();
    // coalesced output pass (the ONLY global writes of this kernel)
    float* ow = out_xyz + (size_t)bt * NS * 3;
    for (int t = tid; t < NS * 3; t += 512) {
        int ii = t / 3, c = t - ii * 3;
        float4 pc = p4[selidx[ii]];
        ow[t] = (c == 0) ? pc.x : (c == 1) ? pc.y : pc.z;
    }
}

// ============================ KNN =============================
// 2 waves/block; wave w owns candidates [w*4096,(w+1)*4096) for the block's
// 64 anchors (one per lane) -> NO in-loop barriers (per-wave LDS state).
// Candidates read directly from global (wave-uniform addr -> scalar/bcast
// loads, frame is L2-resident; no LDS tile). Per lane: sorted main top-32
// (rows 0..31) + append buffer (rows 32..63) + trash row 64, interleaved
// columns. Insert test is 1 f32 cmp: p = !(d2 > rk_f); NaN rk_f (unfilled
// main) keeps inserting; boundary ties admitted and compacted out -- exact
// set since true members have key < rk => d2 <= rk_f.
// Final: bitonic lower-half merge min(st0[i], st1[31-i]) = exact union
// top-32 set (order irrelevant downstream).
__device__ __forceinline__ void knn_compact(u64* st, int lane, int& cnt, float& rk_f)
{
    for (int e = 0; e < 32; ++e)
        if (e >= cnt) st[(e + 32) * 64 + lane] = ~0ull;
    // bitonic sort rows 32..63 ascending (per-lane column, uniform flow)
    for (int k = 2; k <= 32; k <<= 1)
        for (int j = k >> 1; j > 0; j >>= 1)
            for (int i = 0; i < 32; ++i) {
                int l = i ^ j;
                if (l > i) {
                    u64 a = st[(i + 32) * 64 + lane];
                    u64 b = st[(l + 32) * 64 + lane];
                    bool asc = ((i & k) == 0);
                    if ((a > b) == asc) {
                        st[(i + 32) * 64 + lane] = b;
                        st[(l + 32) * 64 + lane] = a;
                    }
                }
            }
    // merge: main[i] vs buf[31-i], keep mins (bitonic lower half)
    for (int i = 0; i < 32; ++i) {
        u64 a = st[i * 64 + lane];
        u64 b = st[(63 - i) * 64 + lane];
        if (b < a) st[i * 64 + lane] = b;
    }
    // re-sort bitonic main ascending: 5 merge passes
    for (int j = 16; j > 0; j >>= 1)
        for (int i = 0; i < 32; ++i) {
            int l = i ^ j;
            if (l > i) {
                u64 a = st[i * 64 + lane];
                u64 b = st[l * 64 + lane];
                if (a > b) {
                    st[i * 64 + lane] = b;
                    st[l * 64 + lane] = a;
                }
            }
        }
    rk_f = __uint_as_float((unsigned)(st[31 * 64 + lane] >> 32));
    cnt = 0;
}

__global__ __launch_bounds__(128)
void knn_kernel(const float* __restrict__ pts,
                const float* __restrict__ anchors,
                unsigned short* __restrict__ knn_out)
{
    const int blk  = blockIdx.x;       // 8bt * 3di * 32 sblk
    const int bt   = blk / 96;
    const int r    = blk % 96;
    const int di   = r / 32;
    const int sblk = r % 32;
    const int b = bt >> 2, t0 = bt & 3;
    int lnb = t0 + di - 1; lnb = lnb < 0 ? 0 : (lnb > 3 ? 3 : lnb);
    const float* nb = pts + (size_t)(b * 4 + lnb) * NPTS * 6;
    const int tid  = threadIdx.x;
    const int w    = tid >> 6;         // wave 0/1: candidate half
    const int lane = tid & 63;
    const int s    = sblk * 64 + lane;

    const float* ap = anchors + ((size_t)bt * NS + s) * 3;
    float ax = ap[0], ay = ap[1], az = ap[2];

    __shared__ u64 st[2][65 * 64];     // 66.5 KB (per-wave state)
    u64* stw = st[w];

    for (int e = 0; e < 64; ++e) stw[e * 64 + lane] = ~0ull;
    float rk_f = __uint_as_float(0x7F800000u);   // +inf
    int cnt = 0;

    const int cbase = w * 4096;
    for (int tb = 0; tb < 4096; tb += 16) {
#pragma unroll
        for (int j = 0; j < 16; ++j) {
            int n = cbase + tb + j;
            float qx = nb[n*6+0], qy = nb[n*6+1], qz = nb[n*6+2]; // uniform
            float dx = __fsub_rn(ax, qx);
            float dy = __fsub_rn(ay, qy);
            float dz = __fsub_rn(az, qz);
            float d2 = __fadd_rn(__fadd_rn(__fmul_rn(dx,dx), __fmul_rn(dy,dy)),
                                 __fmul_rn(dz,dz));
            bool p = !(d2 > rk_f);     // NaN-safe: unfilled main -> insert
            int row = p ? (32 + cnt) : 64;
            stw[row * 64 + lane] =
                ((u64)__float_as_uint(d2) << 32) | (unsigned)n;
            cnt += p ? 1 : 0;
        }
        // pre-batch cnt <= 15, so post-batch cnt <= 31 <= capacity
        if (__any(cnt >= 16)) knn_compact(stw, lane, cnt, rk_f);
    }
    knn_compact(stw, lane, cnt, rk_f);
    __syncthreads();

    if (w == 0) {
        unsigned short* op = knn_out + (((size_t)bt * 3 + di) * NS + s) * KNNK;
#pragma unroll
        for (int e = 0; e < 32; ++e) {
            u64 a = st[0][e * 64 + lane];
            u64 c = st[1][(31 - e) * 64 + lane];
            u64 m = c < a ? c : a;     // lower half of bitonic 64-seq
            op[e] = (unsigned short)(m & 0xFFFFull);
        }
    }
}

// ============================ MLP =============================
// (unchanged from R5/R6 — register-tiled phase 2)
__global__ __launch_bounds__(256)
void mlp_kernel(const float* __restrict__ pts,
                const float* __restrict__ anchors,
                const unsigned short* __restrict__ knn,
                const float* __restrict__ Wd,
                const float* __restrict__ Wm,
                float* __restrict__ out_feats)
{
    const int blk   = blockIdx.x;
    const int bt    = blk >> 10;
    const int spair = blk & 1023;
    const int b = bt >> 2, t0 = bt & 3;
    const int tid = threadIdx.x;
    const int a   = tid >> 7;
    const int r   = tid & 127;
    const int pt  = r & 31;
    const int kt  = r >> 5;
    const int p   = r;
    const int s   = spair * 2 + a;
    const int p0  = pt * 4, k0 = kt * 8;

    __shared__ float WmT[64 * 128];
    __shared__ float Wds[256];
    __shared__ float h1[2][64][32];
    __shared__ float d4s[2][32][4];
    __shared__ float pmax[2][4][128];

    for (int i = tid; i < 8192; i += 256) {
        int pp = i >> 6, oo = i & 63;
        WmT[oo * 128 + pp] = Wm[i];
    }
    Wds[tid & 255] = Wd[tid & 255];

    float fsum = 0.0f;

    for (int dd = 0; dd < 3; ++dd) {
        __syncthreads();
        if (tid < 64) {
            int sa = tid >> 5, k = tid & 31;
            int ss = spair * 2 + sa;
            int lnb = t0 + dd - 1; lnb = lnb < 0 ? 0 : (lnb > 3 ? 3 : lnb);
            const float* nbf = pts + (size_t)(b*4 + lnb) * NPTS * 6;
            const float* ap = anchors + ((size_t)bt * NS + ss) * 3;
            int idx = knn[(((size_t)bt*3 + dd) * NS + ss) * KNNK + k];
            d4s[sa][k][0] = nbf[idx*6+0] - ap[0];
            d4s[sa][k][1] = nbf[idx*6+1] - ap[1];
            d4s[sa][k][2] = nbf[idx*6+2] - ap[2];
            d4s[sa][k][3] = (float)(dd - 1);
        }
        __syncthreads();
        {
            int k  = tid & 31;
            int oq = (tid >> 5) & 3;
            float4 dv = *(const float4*)&d4s[a][k][0];
#pragma unroll
            for (int ii = 0; ii < 16; ++ii) {
                int o = oq * 16 + ii;
                float4 w = *(const float4*)&Wds[o * 4];
                float h = fmaf(dv.x, w.x, fmaf(dv.y, w.y, fmaf(dv.z, w.z, dv.w * w.w)));
                h1[a][o][k] = fmaxf(h, 0.0f);
            }
        }
        __syncthreads();
        float acc[4][8];
#pragma unroll
        for (int i = 0; i < 4; ++i)
#pragma unroll
            for (int j = 0; j < 8; ++j) acc[i][j] = 0.0f;
        for (int o = 0; o < 64; ++o) {
            float4 wv = *(const float4*)&WmT[o * 128 + p0];
            float4 h0 = *(const float4*)&h1[a][o][k0];
            float4 h4 = *(const float4*)&h1[a][o][k0 + 4];
#pragma unroll
            for (int i = 0; i < 4; ++i) {
                float w2 = (i == 0) ? wv.x : (i == 1) ? wv.y : (i == 2) ? wv.z : wv.w;
                acc[i][0] = fmaf(w2, h0.x, acc[i][0]);
                acc[i][1] = fmaf(w2, h0.y, acc[i][1]);
                acc[i][2] = fmaf(w2, h0.z, acc[i][2]);
                acc[i][3] = fmaf(w2, h0.w, acc[i][3]);
                acc[i][4] = fmaf(w2, h4.x, acc[i][4]);
                acc[i][5] = fmaf(w2, h4.y, acc[i][5]);
                acc[i][6] = fmaf(w2, h4.z, acc[i][6]);
                acc[i][7] = fmaf(w2, h4.w, acc[i][7]);
            }
        }
        float4 pm;
#pragma unroll
        for (int i = 0; i < 4; ++i) {
            float m = acc[i][0];
#pragma unroll
            for (int j = 1; j < 8; ++j) m = fmaxf(m, acc[i][j]);
            ((float*)&pm)[i] = m;
        }
        *(float4*)&pmax[a][kt][p0] = pm;
        __syncthreads();
        float m = fmaxf(fmaxf(pmax[a][0][p], pmax[a][1][p]),
                        fmaxf(pmax[a][2][p], pmax[a][3][p]));
        fsum += fmaxf(m, 0.0f);
    }
    out_feats[((size_t)bt * 128 + p) * NS + s] = fsum;
}

// ========================== launcher ==========================
extern "C" void kernel_launch(void* const* d_in, const int* in_sizes, int n_in,
                              void* d_out, int out_size, void* d_ws, size_t ws_size,
                              hipStream_t stream)
{
    const float* pts = (const float*)d_in[0];   // [2,4,8192,6]
    const float* Wd  = (const float*)d_in[1];   // [64,4]
    const float* Wm  = (const float*)d_in[2];   // [128,64]

    float* out_xyz   = (float*)d_out;                 // [2,4,2048,3] == anchors
    float* out_feats = out_xyz + 8 * NS * 3;          // [2,4,128,2048]

    unsigned short* knn = (unsigned short*)d_ws;      // 8*3*2048*32 u16

    fps_kernel<<<8, 512, 0, stream>>>(pts, out_xyz);
    knn_kernel<<<8 * 3 * 32, 128, 0, stream>>>(pts, out_xyz, knn);
    mlp_kernel<<<8 * (NS / 2), 256, 0, stream>>>(pts, out_xyz, knn, Wd, Wm, out_feats);
}

// Round 8
// 3039.465 us; speedup vs baseline: 1.0768x; 1.0768x over previous
//
#include <hip/hip_runtime.h>
#include <stdint.h>

#define NPTS 8192
#define NS   2048
#define KNNK 32

typedef unsigned long long u64;
typedef float f32x2 __attribute__((ext_vector_type(2)));

// DPP-based 64-lane reduces (gfx9 ctrls kept on CDNA). After the 6 steps
// lanes 48..63 hold the full 64-lane result (lane 63 used).
__device__ __forceinline__ float wave_max_f32_dpp(float x) {
    int t;
    t = __builtin_amdgcn_update_dpp(0, __float_as_int(x), 0xB1, 0xF, 0xF, false);
    x = fmaxf(x, __int_as_float(t));
    t = __builtin_amdgcn_update_dpp(0, __float_as_int(x), 0x4E, 0xF, 0xF, false);
    x = fmaxf(x, __int_as_float(t));
    t = __builtin_amdgcn_update_dpp(0, __float_as_int(x), 0x141, 0xF, 0xF, false);
    x = fmaxf(x, __int_as_float(t));
    t = __builtin_amdgcn_update_dpp(0, __float_as_int(x), 0x140, 0xF, 0xF, false);
    x = fmaxf(x, __int_as_float(t));
    // non-written lanes keep old=0; d2>=0 so max(x,0)=x is a no-op
    t = __builtin_amdgcn_update_dpp(0, __float_as_int(x), 0x142, 0xF, 0xF, false);
    x = fmaxf(x, __int_as_float(t));
    t = __builtin_amdgcn_update_dpp(0, __float_as_int(x), 0x143, 0xF, 0xF, false);
    x = fmaxf(x, __int_as_float(t));
    return x;
}

__device__ __forceinline__ int wave_min_i32_dpp(int x) {
    const int INF = 0x7FFFFFFF;
    int t;
    t = __builtin_amdgcn_update_dpp(INF, x, 0xB1, 0xF, 0xF, false);
    x = t < x ? t : x;
    t = __builtin_amdgcn_update_dpp(INF, x, 0x4E, 0xF, 0xF, false);
    x = t < x ? t : x;
    t = __builtin_amdgcn_update_dpp(INF, x, 0x141, 0xF, 0xF, false);
    x = t < x ? t : x;
    t = __builtin_amdgcn_update_dpp(INF, x, 0x140, 0xF, 0xF, false);
    x = t < x ? t : x;
    t = __builtin_amdgcn_update_dpp(INF, x, 0x142, 0xF, 0xF, false);
    x = t < x ? t : x;
    t = __builtin_amdgcn_update_dpp(INF, x, 0x143, 0xF, 0xF, false);
    x = t < x ? t : x;
    return x;
}

// ============================ FPS =============================
// Best-of-all-rounds structure (barrier count is the empirical cost driver:
// R1 3-bar=1.33us/iter, R4 1-bar=0.83, R6/R7 2-bar=0.93):
//   ONE barrier/iter (3-deep ring, R4 proof), LDS-only loop (R7),
//   light reduce (R6/R7): f32 DPP wave-max -> readlane63 -> in-wave
//   16-slot scan + i32 DPP index-min -> ONE u64 atomicMax per wave.
// key = (d2bits<<32)|(8191-idx): argmax with lowest-index tie-break
// (d2>=0 -> f32 bits order-monotone; in-wave min idx over d==waveMax;
// cross-wave via atomicMax low bits) == jnp.argmax semantics exactly.
// Ring: slot (i+1)%3 reset at iter i pre-barrier; its previous readers
// (iter i-2) all passed barrier i-1 before any wave reaches iter i.
// Exact math: rn ops (contract off), sum order ((x+y)+z).
__global__ __launch_bounds__(512)
void fps_kernel(const float* __restrict__ pts,
                float* __restrict__ out_xyz)
{
#pragma clang fp contract(off)
    const int bt  = blockIdx.x;        // b*4 + t0
    const int tid = threadIdx.x;
    const float* frame = pts + (size_t)bt * NPTS * 6;

    __shared__ float4 p4[NPTS];            // 128 KB coords copy
    __shared__ unsigned short selidx[NS];  // 4 KB selection history
    __shared__ u64 ring[3];

    f32x2 x2[8], y2[8], z2[8], dd2[8];
#pragma unroll
    for (int j = 0; j < 16; ++j) {
        int n = j * 512 + tid;
        float x = frame[n*6+0], y = frame[n*6+1], z = frame[n*6+2];
        x2[j >> 1][j & 1] = x;
        y2[j >> 1][j & 1] = y;
        z2[j >> 1][j & 1] = z;
        dd2[j >> 1][j & 1] = 3.4028234663852886e38f;
        p4[n] = make_float4(x, y, z, 0.0f);
    }
    if (tid < 3) ring[tid] = 0;
    if (tid == 0) selidx[0] = 0;       // selection 0 = point 0
    __syncthreads();
    float sx = p4[0].x, sy = p4[0].y, sz = p4[0].z;

    int r = 1;                         // ring slot for iteration i
    for (int i = 1; i < NS; ++i) {
        // packed update vs previous selection, packed min/max accumulate
        f32x2 sxv = {sx, sx}, syv = {sy, sy}, szv = {sz, sz};
        f32x2 m2 = {0.0f, 0.0f};
#pragma unroll
        for (int q = 0; q < 8; ++q) {
            f32x2 dx = x2[q] - sxv;
            f32x2 dy = y2[q] - syv;
            f32x2 dz = z2[q] - szv;
            f32x2 dd = (dx*dx + dy*dy) + dz*dz;
            f32x2 nd;
            nd[0] = fminf(dd2[q][0], dd[0]);
            nd[1] = fminf(dd2[q][1], dd[1]);
            dd2[q] = nd;
            m2[0] = fmaxf(m2[0], nd[0]);
            m2[1] = fmaxf(m2[1], nd[1]);
        }
        float mloc = fmaxf(m2[0], m2[1]);
        // wave max (f32), broadcast via readlane
        float wM = wave_max_f32_dpp(mloc);
        float wMb = __int_as_float(
            __builtin_amdgcn_readlane(__float_as_int(wM), 63));
        // lowest local slot holding wMb (16 independent cmps -> cndmask)
        int bestn = 0x7FFFFFFF;
#pragma unroll
        for (int j = 15; j >= 0; --j)
            bestn = (dd2[j >> 1][j & 1] == wMb) ? (j * 512 + tid) : bestn;
        int wI = wave_min_i32_dpp(bestn);
        if ((tid & 63) == 63) {
            u64 key = ((u64)__float_as_uint(wMb) << 32)
                    | (unsigned)(8191 - wI);
            atomicMax(&ring[r], key);   // ONE atomic per wave
        }
        int rn = r + 1; if (rn == 3) rn = 0;
        if (tid == 0) ring[rn] = 0;    // reset future slot (2 iters away)
        __syncthreads();               // the ONLY barrier per iteration
        u64 k = ring[r];
        int idx = 8191 - (int)(k & 0xFFFFFFFFu);
        if (tid == 0) selidx[i] = (unsigned short)idx;
        float4 c = p4[idx];            // broadcast ds_read_b128
        sx = c.x; sy = c.y; sz = c.z;
        r = rn;
    }
    __syncthreads();
    // coalesced output pass (the ONLY global writes of this kernel)
    float* ow = out_xyz + (size_t)bt * NS * 3;
    for (int t = tid; t < NS * 3; t += 512) {
        int ii = t / 3, c = t - ii * 3;
        float4 pc = p4[selidx[ii]];
        ow[t] = (c == 0) ? pc.x : (c == 1) ? pc.y : pc.z;
    }
}

// ============================ KNN =============================
// REVERTED to the R6 version (R7's no-tile 2-wave variant regressed
// ~790 -> ~1050 us: lost LDS tile reuse + 2x compaction frequency).
// 1 wave/block, one anchor per lane; branchless append + periodic
// bitonic compaction; u64 keys (d2bits<<32|idx) = exact jax top_k set.
__device__ __forceinline__ void knn_compact(u64* st, int lane, int& cnt, u64& rk)
{
    for (int e = 0; e < 32; ++e)
        if (e >= cnt) st[(e + 32) * 64 + lane] = ~0ull;
    for (int k = 2; k <= 32; k <<= 1)
        for (int j = k >> 1; j > 0; j >>= 1)
            for (int i = 0; i < 32; ++i) {
                int l = i ^ j;
                if (l > i) {
                    u64 a = st[(i + 32) * 64 + lane];
                    u64 b = st[(l + 32) * 64 + lane];
                    bool asc = ((i & k) == 0);
                    if ((a > b) == asc) {
                        st[(i + 32) * 64 + lane] = b;
                        st[(l + 32) * 64 + lane] = a;
                    }
                }
            }
    for (int i = 0; i < 32; ++i) {
        u64 a = st[i * 64 + lane];
        u64 b = st[(63 - i) * 64 + lane];
        if (b < a) st[i * 64 + lane] = b;
    }
    for (int j = 16; j > 0; j >>= 1)
        for (int i = 0; i < 32; ++i) {
            int l = i ^ j;
            if (l > i) {
                u64 a = st[i * 64 + lane];
                u64 b = st[l * 64 + lane];
                if (a > b) {
                    st[i * 64 + lane] = b;
                    st[l * 64 + lane] = a;
                }
            }
        }
    rk = st[31 * 64 + lane];
    cnt = 0;
}

__global__ __launch_bounds__(64)
void knn_kernel(const float* __restrict__ pts,
                const float* __restrict__ anchors,
                unsigned short* __restrict__ knn_out)
{
    const int blk  = blockIdx.x;       // 8bt * 3di * 32 sblk
    const int bt   = blk / 96;
    const int r    = blk % 96;
    const int di   = r / 32;
    const int sblk = r % 32;
    const int b = bt >> 2, t0 = bt & 3;
    int lnb = t0 + di - 1; lnb = lnb < 0 ? 0 : (lnb > 3 ? 3 : lnb);
    const float* nb = pts + (size_t)(b * 4 + lnb) * NPTS * 6;
    const int lane = threadIdx.x;
    const int s    = sblk * 64 + lane;

    const float* ap = anchors + ((size_t)bt * NS + s) * 3;
    float ax = ap[0], ay = ap[1], az = ap[2];

    __shared__ u64 st[65 * 64];        // 33.25 KB
    __shared__ float4 tile[512];       // 8 KB

    for (int e = 0; e < 64; ++e) st[e * 64 + lane] = ~0ull;
    u64 rk = ~0ull;
    int cnt = 0;

    for (int tb = 0; tb < NPTS; tb += 512) {
        __syncthreads();
#pragma unroll
        for (int q = 0; q < 8; ++q) {
            int c = q * 64 + lane;
            int n = tb + c;
            tile[c] = make_float4(nb[n*6+0], nb[n*6+1], nb[n*6+2], 0.0f);
        }
        __syncthreads();
        for (int c0 = 0; c0 < 512; c0 += 8) {
#pragma unroll
            for (int j = 0; j < 8; ++j) {
                float4 qv = tile[c0 + j];
                float dx = __fsub_rn(ax, qv.x);
                float dy = __fsub_rn(ay, qv.y);
                float dz = __fsub_rn(az, qv.z);
                float d2 = __fadd_rn(__fadd_rn(__fmul_rn(dx,dx), __fmul_rn(dy,dy)),
                                     __fmul_rn(dz,dz));
                u64 key = ((u64)__float_as_uint(d2) << 32)
                        | (unsigned)(tb + c0 + j);
                bool p = key < rk;
                int row = p ? (32 + cnt) : 64;
                st[row * 64 + lane] = key;
                cnt += p ? 1 : 0;
            }
            if (__any(cnt >= 24)) knn_compact(st, lane, cnt, rk);
        }
    }
    knn_compact(st, lane, cnt, rk);

    unsigned short* op = knn_out + (((size_t)bt * 3 + di) * NS + s) * KNNK;
#pragma unroll
    for (int e = 0; e < 32; ++e)
        op[e] = (unsigned short)(st[e * 64 + lane] & 0xFFFFull);
}

// ============================ MLP =============================
// (unchanged — register-tiled phase 2)
__global__ __launch_bounds__(256)
void mlp_kernel(const float* __restrict__ pts,
                const float* __restrict__ anchors,
                const unsigned short* __restrict__ knn,
                const float* __restrict__ Wd,
                const float* __restrict__ Wm,
                float* __restrict__ out_feats)
{
    const int blk   = blockIdx.x;
    const int bt    = blk >> 10;
    const int spair = blk & 1023;
    const int b = bt >> 2, t0 = bt & 3;
    const int tid = threadIdx.x;
    const int a   = tid >> 7;
    const int r   = tid & 127;
    const int pt  = r & 31;
    const int kt  = r >> 5;
    const int p   = r;
    const int s   = spair * 2 + a;
    const int p0  = pt * 4, k0 = kt * 8;

    __shared__ float WmT[64 * 128];
    __shared__ float Wds[256];
    __shared__ float h1[2][64][32];
    __shared__ float d4s[2][32][4];
    __shared__ float pmax[2][4][128];

    for (int i = tid; i < 8192; i += 256) {
        int pp = i >> 6, oo = i & 63;
        WmT[oo * 128 + pp] = Wm[i];
    }
    Wds[tid & 255] = Wd[tid & 255];

    float fsum = 0.0f;

    for (int dd = 0; dd < 3; ++dd) {
        __syncthreads();
        if (tid < 64) {
            int sa = tid >> 5, k = tid & 31;
            int ss = spair * 2 + sa;
            int lnb = t0 + dd - 1; lnb = lnb < 0 ? 0 : (lnb > 3 ? 3 : lnb);
            const float* nbf = pts + (size_t)(b*4 + lnb) * NPTS * 6;
            const float* ap = anchors + ((size_t)bt * NS + ss) * 3;
            int idx = knn[(((size_t)bt*3 + dd) * NS + ss) * KNNK + k];
            d4s[sa][k][0] = nbf[idx*6+0] - ap[0];
            d4s[sa][k][1] = nbf[idx*6+1] - ap[1];
            d4s[sa][k][2] = nbf[idx*6+2] - ap[2];
            d4s[sa][k][3] = (float)(dd - 1);
        }
        __syncthreads();
        {
            int k  = tid & 31;
            int oq = (tid >> 5) & 3;
            float4 dv = *(const float4*)&d4s[a][k][0];
#pragma unroll
            for (int ii = 0; ii < 16; ++ii) {
                int o = oq * 16 + ii;
                float4 w = *(const float4*)&Wds[o * 4];
                float h = fmaf(dv.x, w.x, fmaf(dv.y, w.y, fmaf(dv.z, w.z, dv.w * w.w)));
                h1[a][o][k] = fmaxf(h, 0.0f);
            }
        }
        __syncthreads();
        float acc[4][8];
#pragma unroll
        for (int i = 0; i < 4; ++i)
#pragma unroll
            for (int j = 0; j < 8; ++j) acc[i][j] = 0.0f;
        for (int o = 0; o < 64; ++o) {
            float4 wv = *(const float4*)&WmT[o * 128 + p0];
            float4 h0 = *(const float4*)&h1[a][o][k0];
            float4 h4 = *(const float4*)&h1[a][o][k0 + 4];
#pragma unroll
            for (int i = 0; i < 4; ++i) {
                float w2 = (i == 0) ? wv.x : (i == 1) ? wv.y : (i == 2) ? wv.z : wv.w;
                acc[i][0] = fmaf(w2, h0.x, acc[i][0]);
                acc[i][1] = fmaf(w2, h0.y, acc[i][1]);
                acc[i][2] = fmaf(w2, h0.z, acc[i][2]);
                acc[i][3] = fmaf(w2, h0.w, acc[i][3]);
                acc[i][4] = fmaf(w2, h4.x, acc[i][4]);
                acc[i][5] = fmaf(w2, h4.y, acc[i][5]);
                acc[i][6] = fmaf(w2, h4.z, acc[i][6]);
                acc[i][7] = fmaf(w2, h4.w, acc[i][7]);
            }
        }
        float4 pm;
#pragma unroll
        for (int i = 0; i < 4; ++i) {
            float m = acc[i][0];
#pragma unroll
            for (int j = 1; j < 8; ++j) m = fmaxf(m, acc[i][j]);
            ((float*)&pm)[i] = m;
        }
        *(float4*)&pmax[a][kt][p0] = pm;
        __syncthreads();
        float m = fmaxf(fmaxf(pmax[a][0][p], pmax[a][1][p]),
                        fmaxf(pmax[a][2][p], pmax[a][3][p]));
        fsum += fmaxf(m, 0.0f);
    }
    out_feats[((size_t)bt * 128 + p) * NS + s] = fsum;
}

// ========================== launcher ==========================
extern "C" void kernel_launch(void* const* d_in, const int* in_sizes, int n_in,
                              void* d_out, int out_size, void* d_ws, size_t ws_size,
                              hipStream_t stream)
{
    const float* pts = (const float*)d_in[0];   // [2,4,8192,6]
    const float* Wd  = (const float*)d_in[1];   // [64,4]
    const float* Wm  = (const float*)d_in[2];   // [128,64]

    float* out_xyz   = (float*)d_out;                 // [2,4,2048,3] == anchors
    float* out_feats = out_xyz + 8 * NS * 3;          // [2,4,128,2048]

    unsigned short* knn = (unsigned short*)d_ws;      // 8*3*2048*32 u16

    fps_kernel<<<8, 512, 0, stream>>>(pts, out_xyz);
    knn_kernel<<<8 * 3 * 32, 64, 0, stream>>>(pts, out_xyz, knn);
    mlp_kernel<<<8 * (NS / 2), 256, 0, stream>>>(pts, out_xyz, knn, Wd, Wm, out_feats);
}